// Round 2
// baseline (127.223 us; speedup 1.0000x reference)
//
#include <hip/hip_runtime.h>

// Chamfer-with-normals, B=8, C=6 (3 pos + 3 nrm), N=4096, fp32.
// d[i][j] = |ap_i|^2 + |bp_j|^2 - 2 ap_i.bp_j + W*(1 - bn_i.an_j)
// (cross-indexed normals: row i uses b's normal, col j uses a's — verified R1, absmax 0).
//
// R2 design: columns are WAVE-UNIFORM -> keep them in SGPRs via uniform s_load
// from a prepacked descriptor buffer (no LDS in the inner loop at all).
// Each thread holds R rows (r = (-2*pos, -W*nrm)) in VGPRs; __launch_bounds__(256,2)
// gives a 256-VGPR budget so nothing spills (R1's VGPR=44 forced AGPR spills).
// Columns processed in pairs so fminf(m,fminf(d1,d2)) folds to v_min3_f32:
// 13 VALU / 2 pairs = 6.5 insts/pair -> ~22 us VALU floor for 268M pairs.

constexpr int   NPTS  = 4096;
constexpr int   CPB   = 6;
constexpr int   BATCH = 8;
constexpr float W     = 0.001f;

// Packed column descriptor: {qx,qy,qz,nx,ny,nz, |q|^2+W, 0} per column.
__global__ __launch_bounds__(256) void prep_kernel(
    const float* __restrict__ A, const float* __restrict__ B,
    float* __restrict__ colpack, float* __restrict__ out)
{
    const int g = blockIdx.x * 256 + threadIdx.x;   // 0 .. 2*BATCH*NPTS
    if (g == 0) out[0] = 0.f;                        // fold zero-init of d_out
    const int j     = g & (NPTS - 1);
    const int db    = g >> 12;                       // dir*BATCH + batch
    const int dir   = db >> 3;
    const int batch = db & 7;
    const float* colPos = dir ? A : B;
    const float* colNrm = dir ? B : A;
    const int bb = batch * CPB * NPTS;
    float qx = colPos[bb + 0*NPTS + j];
    float qy = colPos[bb + 1*NPTS + j];
    float qz = colPos[bb + 2*NPTS + j];
    float nx = colNrm[bb + 3*NPTS + j];
    float ny = colNrm[bb + 4*NPTS + j];
    float nz = colNrm[bb + 5*NPTS + j];
    float bias = fmaf(qx, qx, fmaf(qy, qy, qz * qz)) + W;
    float4 v0 = make_float4(qx, qy, qz, nx);
    float4 v1 = make_float4(ny, nz, bias, 0.f);
    float* cp = colpack + (size_t)g * 8;
    *reinterpret_cast<float4*>(cp)     = v0;
    *reinterpret_cast<float4*>(cp + 4) = v1;
}

template<int CHUNKS, int R>
__global__ __launch_bounds__(256, 2) void chamfer_min_kernel(
    const float* __restrict__ A, const float* __restrict__ B,
    const float* __restrict__ colpack, float* __restrict__ partial)
{
    constexpr int TJ     = NPTS / CHUNKS;
    constexpr int ROWBLK = R * 256;
    const int dir   = blockIdx.z;
    const int batch = blockIdx.y;
    const int chunk = blockIdx.x % CHUNKS;
    const int rb    = blockIdx.x / CHUNKS;
    const float* rowPos = dir ? B : A;
    const float* rowNrm = dir ? A : B;
    const int bb  = batch * CPB * NPTS;
    const int tid = threadIdx.x;
    const int rowBase = rb * ROWBLK;

    float r[R][6], m[R];
#pragma unroll
    for (int k = 0; k < R; ++k) {
        const int row = rowBase + k * 256 + tid;     // coalesced channel loads
        r[k][0] = -2.f * rowPos[bb + 0*NPTS + row];
        r[k][1] = -2.f * rowPos[bb + 1*NPTS + row];
        r[k][2] = -2.f * rowPos[bb + 2*NPTS + row];
        r[k][3] = -W   * rowNrm[bb + 3*NPTS + row];
        r[k][4] = -W   * rowNrm[bb + 4*NPTS + row];
        r[k][5] = -W   * rowNrm[bb + 5*NPTS + row];
        m[k] = 3.4e38f;
    }

    // Wave-uniform column stream: uniform address + __restrict__ (no aliasing
    // stores) -> scalar s_load_dwordx4/x8; columns live in SGPRs, zero LDS.
    const float* __restrict__ cp =
        colpack + ((size_t)(dir * BATCH + batch) * NPTS + chunk * TJ) * 8;

#pragma unroll 2
    for (int jj = 0; jj < TJ; jj += 2) {
        const float4 c0 = *reinterpret_cast<const float4*>(cp + (size_t)jj*8);
        const float4 c1 = *reinterpret_cast<const float4*>(cp + (size_t)jj*8 + 4);
        const float4 e0 = *reinterpret_cast<const float4*>(cp + (size_t)jj*8 + 8);
        const float4 e1 = *reinterpret_cast<const float4*>(cp + (size_t)jj*8 + 12);
#pragma unroll
        for (int k = 0; k < R; ++k) {
            float d1 = fmaf(r[k][0], c0.x, c1.z);
            d1 = fmaf(r[k][1], c0.y, d1);
            d1 = fmaf(r[k][2], c0.z, d1);
            d1 = fmaf(r[k][3], c0.w, d1);
            d1 = fmaf(r[k][4], c1.x, d1);
            d1 = fmaf(r[k][5], c1.y, d1);
            float d2 = fmaf(r[k][0], e0.x, e1.z);
            d2 = fmaf(r[k][1], e0.y, d2);
            d2 = fmaf(r[k][2], e0.z, d2);
            d2 = fmaf(r[k][3], e0.w, d2);
            d2 = fmaf(r[k][4], e1.x, d2);
            d2 = fmaf(r[k][5], e1.y, d2);
            m[k] = fminf(m[k], fminf(d1, d2));       // -> v_min3_f32
        }
    }

    // Fold the deferred row bias |p_i|^2 = ((-2p)^2)/4 here (epilogue-only cost)
    float* p = partial + ((size_t)(dir * BATCH + batch) * CHUNKS + chunk) * NPTS;
#pragma unroll
    for (int k = 0; k < R; ++k) {
        float bias = 0.25f * fmaf(r[k][0], r[k][0],
                           fmaf(r[k][1], r[k][1], r[k][2] * r[k][2]));
        p[rowBase + k * 256 + tid] = m[k] + bias;
    }
}

template<int CHUNKS>
__global__ __launch_bounds__(256) void chamfer_reduce_kernel(
    const float* __restrict__ partial, float* __restrict__ out)
{
    const int dir   = blockIdx.z;
    const int batch = blockIdx.y;
    const int row   = blockIdx.x * 256 + threadIdx.x;
    const float* p = partial + (size_t)(dir * BATCH + batch) * CHUNKS * NPTS;

    float m = 3.4e38f;
#pragma unroll
    for (int c = 0; c < CHUNKS; ++c)
        m = fminf(m, p[c * NPTS + row]);

    float v = m;
    for (int off = 32; off; off >>= 1)
        v += __shfl_down(v, off, 64);
    __shared__ float sred[4];
    if ((threadIdx.x & 63) == 0) sred[threadIdx.x >> 6] = v;
    __syncthreads();
    if (threadIdx.x == 0)
        atomicAdd(out, (sred[0] + sred[1] + sred[2] + sred[3]) * 0.125f); // /B
}

extern "C" void kernel_launch(void* const* d_in, const int* in_sizes, int n_in,
                              void* d_out, int out_size, void* d_ws, size_t ws_size,
                              hipStream_t stream) {
    const float* A = (const float*)d_in[0];
    const float* B = (const float*)d_in[1];
    float* out     = (float*)d_out;

    float* colpack = (float*)d_ws;                               // 2 MB
    const size_t colpackF = (size_t)2 * BATCH * NPTS * 8;        // floats
    float* partial = colpack + colpackF;

    prep_kernel<<<dim3(2 * BATCH * NPTS / 256), 256, 0, stream>>>(A, B, colpack, out);

    const size_t colpackB  = colpackF * sizeof(float);
    const size_t partialB16 = (size_t)2 * BATCH * 16 * NPTS * sizeof(float); // 4 MB
    const size_t partialB8  = partialB16 / 2;                                // 2 MB
    // grid.x = (NPTS/(R*256)) * CHUNKS = 32 for all tiers
    if (ws_size >= colpackB + partialB16) {
        chamfer_min_kernel<16, 8><<<dim3(32, BATCH, 2), 256, 0, stream>>>(A, B, colpack, partial);
        chamfer_reduce_kernel<16><<<dim3(NPTS / 256, BATCH, 2), 256, 0, stream>>>(partial, out);
    } else if (ws_size >= colpackB + partialB8) {
        chamfer_min_kernel<8, 4><<<dim3(32, BATCH, 2), 256, 0, stream>>>(A, B, colpack, partial);
        chamfer_reduce_kernel<8><<<dim3(NPTS / 256, BATCH, 2), 256, 0, stream>>>(partial, out);
    } else {
        chamfer_min_kernel<4, 2><<<dim3(32, BATCH, 2), 256, 0, stream>>>(A, B, colpack, partial);
        chamfer_reduce_kernel<4><<<dim3(NPTS / 256, BATCH, 2), 256, 0, stream>>>(partial, out);
    }
}

// Round 3
// 96.111 us; speedup vs baseline: 1.3237x; 1.3237x over previous
//
#include <hip/hip_runtime.h>

// Chamfer-with-normals, B=8, C=6 (3 pos + 3 nrm), N=4096, fp32.
// d[i][j] = |ap_i|^2 + |bp_j|^2 - 2 ap_i.bp_j + W*(1 - bn_i.an_j)
// (cross-indexed normals: row i uses b's normal, col j uses a's — verified R1, absmax 0).
//
// R3: back to R1's LDS-broadcast column staging (beat R2's s_load path), with the
// AGPR-spill inflation fixed: __launch_bounds__(256,4) gives a 128-VGPR budget so
// r[8][6]+m[8]+col regs (~90) live in arch VGPRs — R1/R2 had VGPR_Count 44/36 < 48
// row floats, i.e. rows in AGPRs with a v_accvgpr_read per fma operand (~1.85x
// VALU inflation, measured). Columns paired so fminf(m,fminf(d1,d2)) -> v_min3_f32:
// 6.5 insts/pair, 268M pairs -> ~22 us VALU floor.
// Dispatches cut 3 -> 2: out=0 folded into min kernel (same-value race, ordered
// before reduce's atomics by the stream edge); row bias folded into min epilogue
// (bitwise-identical: x -> fl(x+b) is monotone).

constexpr int   NPTS  = 4096;
constexpr int   CPB   = 6;
constexpr int   BATCH = 8;
constexpr float W     = 0.001f;

template<int CHUNKS>
__global__ __launch_bounds__(256, 4) void chamfer_min_kernel(
    const float* __restrict__ A, const float* __restrict__ B,
    float* __restrict__ partial, float* __restrict__ out)
{
    constexpr int TJ = NPTS / CHUNKS;
    const int dir   = blockIdx.z;
    const int batch = blockIdx.y;
    const int chunk = blockIdx.x % CHUNKS;
    const int rb    = blockIdx.x / CHUNKS;     // row block (2048 rows each)
    const float* rowPos = dir ? B : A;
    const float* rowNrm = dir ? A : B;
    const float* colPos = dir ? A : B;
    const float* colNrm = dir ? B : A;
    const int bb  = batch * CPB * NPTS;
    const int tid = threadIdx.x;

    if (blockIdx.x == 0 && blockIdx.y == 0 && blockIdx.z == 0 && tid == 0)
        out[0] = 0.f;                           // zero-init for reduce's atomics

    __shared__ float cols[TJ][8];
    for (int j = tid; j < TJ; j += 256) {
        const int cj = chunk * TJ + j;
        float qx = colPos[bb + 0*NPTS + cj];
        float qy = colPos[bb + 1*NPTS + cj];
        float qz = colPos[bb + 2*NPTS + cj];
        float nx = colNrm[bb + 3*NPTS + cj];
        float ny = colNrm[bb + 4*NPTS + cj];
        float nz = colNrm[bb + 5*NPTS + cj];
        cols[j][0] = qx; cols[j][1] = qy; cols[j][2] = qz;
        cols[j][3] = nx; cols[j][4] = ny; cols[j][5] = nz;
        cols[j][6] = fmaf(qx, qx, fmaf(qy, qy, qz*qz)) + W;   // col bias (+W once)
        cols[j][7] = 0.f;
    }

    float r[8][6], m[8];
    const int rowBase = rb * 2048;
#pragma unroll
    for (int k = 0; k < 8; ++k) {
        const int row = rowBase + k*256 + tid;  // strided: coalesced channel loads
        r[k][0] = -2.f * rowPos[bb + 0*NPTS + row];
        r[k][1] = -2.f * rowPos[bb + 1*NPTS + row];
        r[k][2] = -2.f * rowPos[bb + 2*NPTS + row];
        r[k][3] = -W   * rowNrm[bb + 3*NPTS + row];
        r[k][4] = -W   * rowNrm[bb + 4*NPTS + row];
        r[k][5] = -W   * rowNrm[bb + 5*NPTS + row];
        m[k] = 3.4e38f;
    }
    __syncthreads();

#pragma unroll 2
    for (int jj = 0; jj < TJ; jj += 2) {
        const float4 c0 = *reinterpret_cast<const float4*>(&cols[jj][0]);
        const float4 c1 = *reinterpret_cast<const float4*>(&cols[jj][4]);
        const float4 e0 = *reinterpret_cast<const float4*>(&cols[jj + 1][0]);
        const float4 e1 = *reinterpret_cast<const float4*>(&cols[jj + 1][4]);
#pragma unroll
        for (int k = 0; k < 8; ++k) {
            float d1 = fmaf(r[k][0], c0.x, c1.z);
            d1 = fmaf(r[k][1], c0.y, d1);
            d1 = fmaf(r[k][2], c0.z, d1);
            d1 = fmaf(r[k][3], c0.w, d1);
            d1 = fmaf(r[k][4], c1.x, d1);
            d1 = fmaf(r[k][5], c1.y, d1);
            float d2 = fmaf(r[k][0], e0.x, e1.z);
            d2 = fmaf(r[k][1], e0.y, d2);
            d2 = fmaf(r[k][2], e0.z, d2);
            d2 = fmaf(r[k][3], e0.w, d2);
            d2 = fmaf(r[k][4], e1.x, d2);
            d2 = fmaf(r[k][5], e1.y, d2);
            m[k] = fminf(m[k], fminf(d1, d2));  // -> v_min3_f32
        }
    }

    // Fold deferred row bias |p_i|^2 = ((-2p)^2)/4 here (epilogue-only cost)
    float* p = partial + ((size_t)(dir * BATCH + batch) * CHUNKS + chunk) * NPTS;
#pragma unroll
    for (int k = 0; k < 8; ++k) {
        const float bias = 0.25f * fmaf(r[k][0], r[k][0],
                                 fmaf(r[k][1], r[k][1], r[k][2] * r[k][2]));
        p[rowBase + k*256 + tid] = m[k] + bias;
    }
}

template<int CHUNKS>
__global__ __launch_bounds__(256) void chamfer_reduce_kernel(
    const float* __restrict__ partial, float* __restrict__ out)
{
    const int dir   = blockIdx.z;
    const int batch = blockIdx.y;
    const int half  = blockIdx.x;               // 2 halves of 2048 rows
    const int tid   = threadIdx.x;
    const float* p = partial + (size_t)(dir * BATCH + batch) * CHUNKS * NPTS;

    float v = 0.f;
#pragma unroll
    for (int s = 0; s < 8; ++s) {
        const int row = half * 2048 + s * 256 + tid;
        float m = 3.4e38f;
#pragma unroll
        for (int c = 0; c < CHUNKS; ++c)
            m = fminf(m, p[c * NPTS + row]);
        v += m;
    }
    for (int off = 32; off; off >>= 1)
        v += __shfl_down(v, off, 64);
    __shared__ float sred[4];
    if ((tid & 63) == 0) sred[tid >> 6] = v;
    __syncthreads();
    if (tid == 0)
        atomicAdd(out, (sred[0] + sred[1] + sred[2] + sred[3]) * 0.125f); // /B
}

extern "C" void kernel_launch(void* const* d_in, const int* in_sizes, int n_in,
                              void* d_out, int out_size, void* d_ws, size_t ws_size,
                              hipStream_t stream) {
    const float* A = (const float*)d_in[0];
    const float* B = (const float*)d_in[1];
    float* out     = (float*)d_out;
    float* partial = (float*)d_ws;

    const size_t chunkB = (size_t)2 * BATCH * NPTS * sizeof(float);  // 0.25 MB per chunk
    if (ws_size >= 16 * chunkB) {
        chamfer_min_kernel<16><<<dim3(32, BATCH, 2), 256, 0, stream>>>(A, B, partial, out);
        chamfer_reduce_kernel<16><<<dim3(2, BATCH, 2), 256, 0, stream>>>(partial, out);
    } else if (ws_size >= 8 * chunkB) {
        chamfer_min_kernel<8><<<dim3(16, BATCH, 2), 256, 0, stream>>>(A, B, partial, out);
        chamfer_reduce_kernel<8><<<dim3(2, BATCH, 2), 256, 0, stream>>>(partial, out);
    } else {
        chamfer_min_kernel<4><<<dim3(8, BATCH, 2), 256, 0, stream>>>(A, B, partial, out);
        chamfer_reduce_kernel<4><<<dim3(2, BATCH, 2), 256, 0, stream>>>(partial, out);
    }
}